// Round 6
// baseline (267.091 us; speedup 1.0000x reference)
//
#include <hip/hip_runtime.h>

#define BH (512*2048)
#define BHA 1048576ull                   // 512*2048 elems (one activation plane)
#define PPLANE (512ull*8192ull)          // elems per partial plane [512][8192]
#define PLANE_BYTES (PPLANE*2ull)        // bf16
#define AB_ELEMS (2ull*512*2048)         // bf16 activations (inputs + prevstate)

typedef __attribute__((ext_vector_type(8))) short short8;
typedef __attribute__((ext_vector_type(4))) float floatx4;
typedef __attribute__((ext_vector_type(2))) float floatx2;
typedef __attribute__((ext_vector_type(4))) unsigned int uint4v;
typedef __attribute__((ext_vector_type(8))) unsigned short ushort8v;

// pack two f32 -> two bf16 (round-half-up) in one dword (verified R2-R4)
__device__ inline unsigned pk2(float a, float b){
    unsigned ua = __builtin_bit_cast(unsigned, a) + 0x8000u;
    unsigned ub = __builtin_bit_cast(unsigned, b) + 0x8000u;
    return __builtin_amdgcn_perm(ub, ua, 0x07060302u);
}
__device__ inline unsigned short f2bf1(float x){
    return (unsigned short)((__builtin_bit_cast(unsigned, x) + 0x8000u) >> 16);
}
__device__ inline float bf2f(unsigned short s){
    return __builtin_bit_cast(float, ((unsigned)s) << 16);
}
__device__ inline int swz(int r, int g){ return r*4 + (g ^ ((r>>1)&3)); }
__device__ inline float fsig(float x){ return __builtin_amdgcn_rcpf(1.f + __expf(-x)); }
__device__ inline float ftanh(float x){ return 2.f*fsig(2.f*x) - 1.f; }

// ---------------------------------------------------------------------------
// Activation cast only. Casts inputs (plane 0) and states[0] (plane 1) to
// bf16 flat. 1024 blocks.
// ---------------------------------------------------------------------------
__global__ __launch_bounds__(256) void prep_act(
    const float* __restrict__ inputs, const float* __restrict__ states,
    unsigned short* __restrict__ Ab)
{
    const size_t off = ((size_t)blockIdx.x * 256 + threadIdx.x) * 8;
    const float* src = (off < BHA) ? (inputs + off) : (states + (off - BHA));
    floatx4 v0 = *(const floatx4*)src;
    floatx4 v1 = *(const floatx4*)(src + 4);
    uint4v w;
    w.x = pk2(v0[0],v0[1]); w.y = pk2(v0[2],v0[3]);
    w.z = pk2(v1[0],v1[1]); w.w = pk2(v1[2],v1[3]);
    *(uint4v*)(Ab + off) = w;
}

// ---------------------------------------------------------------------------
// Fused GEMM R6: A fragments loaded DIRECT from global bf16 Ab (no LDS for A
// at all — the per-iter 8KB A-slab is L1-resident, shared by the 4 waves and
// by the 64 x-blocks via L2). B: 8x coalesced dwordx2 fp32 loads per thread
// (thread owns cols n0,n0+1 x one k-octet), pk2 -> 2x ds_write_b128 into the
// PROVEN [n][granule ^ ((n>>1)&3)] layout (R2/R4, 0 read conflicts).
// Sync: R4's proven raw-barrier pipeline (lgkmcnt(0) + s_barrier +
// sched_barrier(0); global loads never drained — compiler emits counted
// vmcnt from data deps). 2-deep B reg pipeline, 1-deep A frag prefetch.
// Block 128x128, 4 waves of 64x64 (4x4 x mfma_16x16x32_bf16), BK=32,
// grid (64 n-panels, 4 m-blocks, 4 K-chunks). LDS = Bs only (16KB).
// ---------------------------------------------------------------------------
__global__ __launch_bounds__(256, 2) void gemm_fused(
    const float* __restrict__ Wi, const float* __restrict__ Ui,
    const float* __restrict__ Wf, const float* __restrict__ Uf,
    const float* __restrict__ Wg, const float* __restrict__ Ug,
    const float* __restrict__ Wc, const float* __restrict__ Uc,
    const unsigned short* __restrict__ Ab, unsigned short* __restrict__ P)
{
    __shared__ unsigned short Bs[2][4096];   // [n 0..127][granule-XOR k]

    const int t = threadIdx.x, lane = t & 63, wave = t >> 6;
    const int nblk = blockIdx.x, gate = nblk >> 4, nbx = nblk & 15;
    const int m0 = blockIdx.y * 128, z = blockIdx.z;
    const int ko = (z & 1) * 1024;

    const float* Bsel;
    if (z < 2) { switch (gate){ case 0: Bsel=Wi; break; case 1: Bsel=Wf; break;
                                case 2: Bsel=Wg; break; default: Bsel=Wc; } }
    else       { switch (gate){ case 0: Bsel=Ui; break; case 1: Bsel=Uf; break;
                                case 2: Bsel=Ug; break; default: Bsel=Uc; } }

    // ---- B staging: thread owns cols n0,n0+1 and k-octet = wave ----
    const int n0  = lane * 2;            // 0..126 even
    const int oct = wave;                // 0..3 (granule index)
    const float* Bp = Bsel + (size_t)(ko + oct * 8) * 2048 + nbx * 128 + n0;
    const int keyB = lane & 3;           // (n0>>1)&3
    const int wb0 = n0 * 32 + ((oct ^ keyB) << 3);       // row n0 (shorts)
    const int wb1 = wb0 + 32;                            // row n0+1

    const int wm = (wave & 1) * 64, wn = (wave >> 1) * 64;
    const int row16 = lane & 15, g4 = lane >> 4;
    const int fgx = (g4 ^ ((row16 >> 1) & 3)) << 3;      // proven B frag offset

    // ---- A direct-frag base: lane reads rows (m0+wm+mi*16+row16), k-octet g4
    const unsigned short* Ap = Ab + (size_t)(z >> 1) * BHA
                             + (size_t)(m0 + wm + row16) * 2048
                             + (z & 1) * 1024 + g4 * 8;

    floatx4 acc[4][4];
    #pragma unroll
    for (int i = 0; i < 4; i++)
        #pragma unroll
        for (int j = 0; j < 4; j++)
            acc[i][j] = (floatx4){0.f,0.f,0.f,0.f};

    floatx2 q0[8], q1[8];        // B reg sets (tile kk+2 / kk+3)
    short8 fA[4], fB[4];         // A frag sets (even / odd tiles)

#define B_LOAD(d, tile) do { \
    const float* bp_ = Bp + (size_t)(tile) * 65536; \
    _Pragma("unroll") for (int j = 0; j < 8; j++) \
        d[j] = *(const floatx2*)(bp_ + (size_t)j * 2048); \
} while(0)

#define B_WRITE(buf, s) do { \
    *(uint4v*)&Bs[buf][wb0] = (uint4v){pk2(s[0].x,s[1].x), pk2(s[2].x,s[3].x), \
                                       pk2(s[4].x,s[5].x), pk2(s[6].x,s[7].x)}; \
    *(uint4v*)&Bs[buf][wb1] = (uint4v){pk2(s[0].y,s[1].y), pk2(s[2].y,s[3].y), \
                                       pk2(s[4].y,s[5].y), pk2(s[6].y,s[7].y)}; \
} while(0)

#define A_LOADF(f, tile) do { \
    _Pragma("unroll") for (int mi = 0; mi < 4; mi++) \
        f[mi] = *(const short8*)(Ap + (size_t)mi * 32768 + (size_t)(tile) * 32); \
} while(0)

#define MFMA_STEP(buf, f) do { \
    short8 bfr[4]; \
    _Pragma("unroll") for (int ni = 0; ni < 4; ni++) \
        bfr[ni] = *(const short8*)&Bs[buf][(wn + ni*16 + row16)*32 + fgx]; \
    _Pragma("unroll") for (int mi = 0; mi < 4; mi++) \
        _Pragma("unroll") for (int ni = 0; ni < 4; ni++) \
            acc[mi][ni] = __builtin_amdgcn_mfma_f32_16x16x32_bf16( \
                f[mi], bfr[ni], acc[mi][ni], 0, 0, 0); \
} while(0)

// ds_writes visible without draining global loads (proven R4).
#define PIPEBAR() do { \
    asm volatile("s_waitcnt lgkmcnt(0)" ::: "memory"); \
    __builtin_amdgcn_s_barrier(); \
    __builtin_amdgcn_sched_barrier(0); \
} while(0)

    // ---- prologue: B tiles 0,1 -> sets; A tiles 0,1 -> frag sets ----
    B_LOAD(q0, 0);
    B_LOAD(q1, 1);
    A_LOADF(fA, 0);
    A_LOADF(fB, 1);
    B_WRITE(0, q0);              // Bs[0] <- tile 0 (waits q0 only)
    PIPEBAR();

    for (int kk = 0; kk < 32; kk += 2) {
        // even iter kk: compute Bs[0]=tile kk with fA
        if (kk < 30) B_LOAD(q0, kk + 2);
        MFMA_STEP(0, fA);
        B_WRITE(1, q1);          // tile kk+1 (loaded a full iter ago)
        if (kk < 30) A_LOADF(fA, kk + 2);
        PIPEBAR();
        // odd iter kk+1: compute Bs[1]=tile kk+1 with fB
        if (kk < 30) B_LOAD(q1, kk + 3);
        MFMA_STEP(1, fB);
        if (kk < 30) {
            B_WRITE(0, q0);      // tile kk+2
            A_LOADF(fB, kk + 3);
        }
        PIPEBAR();
    }

#undef B_LOAD
#undef B_WRITE
#undef A_LOADF
#undef MFMA_STEP
#undef PIPEBAR

    unsigned short* dst = P + (size_t)z * PPLANE;
    const int gbase = gate * 2048 + nbx * 128;
    #pragma unroll
    for (int mi = 0; mi < 4; mi++)
        #pragma unroll
        for (int ni = 0; ni < 4; ni++)
            #pragma unroll
            for (int j = 0; j < 4; j++) {
                int row = m0 + wm + mi*16 + g4*4 + j;
                int col = gbase + wn + ni*16 + row16;
                dst[(size_t)row * 8192 + col] = f2bf1(acc[mi][ni][j]);
            }
}

// ---------------------------------------------------------------------------
// Fallback GEMM (fused fp32 staging) for small ws_size.
// ---------------------------------------------------------------------------
__global__ __launch_bounds__(256, 2) void gemm_tile(
    const float* __restrict__ inputs, const float* __restrict__ states,
    const float* __restrict__ Wi, const float* __restrict__ Ui,
    const float* __restrict__ Wf, const float* __restrict__ Uf,
    const float* __restrict__ Wg, const float* __restrict__ Ug,
    const float* __restrict__ Wc, const float* __restrict__ Uc,
    unsigned short* __restrict__ P, int KB)
{
    __shared__ uint4v As[2][512];
    __shared__ uint4v Bs[2][512];

    const int t = threadIdx.x;
    const int m0 = blockIdx.y * 128;
    const int z = blockIdx.z;
    const int nblk = blockIdx.x;
    const int gate = nblk >> 4;
    const int c0 = (nblk & 15) * 128;
    const int gk = z * KB;

    const float* Abase; const float* Bsel; int ko;
    if (gk < 2048) {
        Abase = inputs; ko = gk;
        switch (gate){ case 0: Bsel=Wi; break; case 1: Bsel=Wf; break;
                       case 2: Bsel=Wg; break; default: Bsel=Wc; }
    } else {
        Abase = states; ko = gk - 2048;
        switch (gate){ case 0: Bsel=Ui; break; case 1: Bsel=Uf; break;
                       case 2: Bsel=Ug; break; default: Bsel=Uc; }
    }
    const int NIT = KB >> 5;

    const int lane = t & 63, wave = t >> 6;
    const int wm = (wave & 1) * 64, wn = (wave >> 1) * 64;
    const int row16 = lane & 15, g4 = lane >> 4;
    const int ar = t >> 2, ag = t & 3;
    const int bn = t & 127, bg2 = (t >> 7) * 2;

    const float* Ap = Abase + (size_t)(m0 + ar) * 2048 + ko + ag * 8;
    const float* Bp = Bsel + (size_t)ko * 2048 + c0 + bn;

    floatx4 acc[4][4];
    #pragma unroll
    for (int i = 0; i < 4; i++)
        #pragma unroll
        for (int j = 0; j < 4; j++)
            acc[i][j] = (floatx4){0.f,0.f,0.f,0.f};

    floatx4 a0,a1,a2,a3; float b0[8], b1[8];
    a0 = *(const floatx4*)Ap;             a1 = *(const floatx4*)(Ap + 4);
    a2 = *(const floatx4*)(Ap + 64*2048); a3 = *(const floatx4*)(Ap + 64*2048 + 4);
    #pragma unroll
    for (int j = 0; j < 8; j++) b0[j] = Bp[(size_t)(bg2*8 + j) * 2048];
    #pragma unroll
    for (int j = 0; j < 8; j++) b1[j] = Bp[(size_t)(bg2*8 + 8 + j) * 2048];
    {
        uint4v w;
        w.x=pk2(a0[0],a0[1]); w.y=pk2(a0[2],a0[3]); w.z=pk2(a1[0],a1[1]); w.w=pk2(a1[2],a1[3]);
        As[0][swz(ar, ag)] = w;
        w.x=pk2(a2[0],a2[1]); w.y=pk2(a2[2],a2[3]); w.z=pk2(a3[0],a3[1]); w.w=pk2(a3[2],a3[3]);
        As[0][swz(ar+64, ag)] = w;
        w.x=pk2(b0[0],b0[1]); w.y=pk2(b0[2],b0[3]); w.z=pk2(b0[4],b0[5]); w.w=pk2(b0[6],b0[7]);
        Bs[0][swz(bn, bg2)] = w;
        w.x=pk2(b1[0],b1[1]); w.y=pk2(b1[2],b1[3]); w.z=pk2(b1[4],b1[5]); w.w=pk2(b1[6],b1[7]);
        Bs[0][swz(bn, bg2+1)] = w;
    }

    for (int kk = 0; kk < NIT; kk++) {
        __syncthreads();
        const int cur = kk & 1;
        if (kk + 1 < NIT) {
            const float* ap = Ap + (kk+1) * 32;
            a0 = *(const floatx4*)ap;             a1 = *(const floatx4*)(ap + 4);
            a2 = *(const floatx4*)(ap + 64*2048); a3 = *(const floatx4*)(ap + 64*2048 + 4);
            const float* bp = Bp + (size_t)(kk+1) * 32 * 2048;
            #pragma unroll
            for (int j = 0; j < 8; j++) b0[j] = bp[(size_t)(bg2*8 + j) * 2048];
            #pragma unroll
            for (int j = 0; j < 8; j++) b1[j] = bp[(size_t)(bg2*8 + 8 + j) * 2048];
        }
        short8 afr[4], bfr[4];
        #pragma unroll
        for (int mi = 0; mi < 4; mi++)
            afr[mi] = *(const short8*)&As[cur][swz(wm + mi*16 + row16, g4)];
        #pragma unroll
        for (int ni = 0; ni < 4; ni++)
            bfr[ni] = *(const short8*)&Bs[cur][swz(wn + ni*16 + row16, g4)];
        #pragma unroll
        for (int mi = 0; mi < 4; mi++)
            #pragma unroll
            for (int ni = 0; ni < 4; ni++)
                acc[mi][ni] = __builtin_amdgcn_mfma_f32_16x16x32_bf16(
                    afr[mi], bfr[ni], acc[mi][ni], 0, 0, 0);
        if (kk + 1 < NIT) {
            const int nxt = cur ^ 1;
            uint4v w;
            w.x=pk2(a0[0],a0[1]); w.y=pk2(a0[2],a0[3]); w.z=pk2(a1[0],a1[1]); w.w=pk2(a1[2],a1[3]);
            As[nxt][swz(ar, ag)] = w;
            w.x=pk2(a2[0],a2[1]); w.y=pk2(a2[2],a2[3]); w.z=pk2(a3[0],a3[1]); w.w=pk2(a3[2],a3[3]);
            As[nxt][swz(ar+64, ag)] = w;
            w.x=pk2(b0[0],b0[1]); w.y=pk2(b0[2],b0[3]); w.z=pk2(b0[4],b0[5]); w.w=pk2(b0[6],b0[7]);
            Bs[nxt][swz(bn, bg2)] = w;
            w.x=pk2(b1[0],b1[1]); w.y=pk2(b1[2],b1[3]); w.z=pk2(b1[4],b1[5]); w.w=pk2(b1[6],b1[7]);
            Bs[nxt][swz(bn, bg2+1)] = w;
        }
    }

    unsigned short* dst = P + (size_t)z * PPLANE;
    const int gbase = gate * 2048 + c0;
    #pragma unroll
    for (int mi = 0; mi < 4; mi++)
        #pragma unroll
        for (int ni = 0; ni < 4; ni++)
            #pragma unroll
            for (int j = 0; j < 4; j++) {
                int row = m0 + wm + mi*16 + g4*4 + j;
                int col = gbase + wn + ni*16 + row16;
                dst[(size_t)row * 8192 + col] = f2bf1(acc[mi][ni][j]);
            }
}

// activations + LSTM combine
__global__ __launch_bounds__(256) void combine_kernel(
    float* __restrict__ out, const unsigned short* __restrict__ P,
    const float* __restrict__ states,
    const float* __restrict__ bi, const float* __restrict__ bfv,
    const float* __restrict__ bg, const float* __restrict__ bc, int nz)
{
    const int idx = (blockIdx.x * 256 + threadIdx.x) * 8;
    const int row = idx >> 11;
    const int h = idx & 2047;
    const size_t base = (size_t)row * 8192 + h;

    float xi[8], xf[8], xg[8], xc[8];
    #pragma unroll
    for (int e = 0; e < 8; e++) {
        xi[e] = bi[h+e]; xf[e] = bfv[h+e]; xg[e] = bg[h+e]; xc[e] = bc[h+e];
    }
    for (int z = 0; z < nz; z++) {
        const unsigned short* Pz = P + (size_t)z * PPLANE;
        ushort8v vi = *(const ushort8v*)&Pz[base];
        ushort8v vf = *(const ushort8v*)&Pz[base + 2048];
        ushort8v vg = *(const ushort8v*)&Pz[base + 4096];
        ushort8v vc = *(const ushort8v*)&Pz[base + 6144];
        #pragma unroll
        for (int e = 0; e < 8; e++) {
            xi[e] += bf2f(vi[e]); xf[e] += bf2f(vf[e]);
            xg[e] += bf2f(vg[e]); xc[e] += bf2f(vc[e]);
        }
    }

    const float* po = states + BH;
    floatx4 pov[2];
    pov[0] = *(const floatx4*)&po[idx];
    pov[1] = *(const floatx4*)&po[idx + 4];

    floatx4 vcv[2], vsv[2];
    #pragma unroll
    for (int q = 0; q < 2; q++)
        #pragma unroll
        for (int j = 0; j < 4; j++) {
            int e = q*4 + j;
            float c = fsig(xf[e]) * pov[q][j] + fsig(xi[e]) * ftanh(xc[e]);
            vcv[q][j] = c;
            vsv[q][j] = fsig(xg[e]) * ftanh(c);
        }
    #pragma unroll
    for (int q = 0; q < 2; q++) {
        *(floatx4*)&out[idx + q*4]        = vcv[q];
        *(floatx4*)&out[BH + idx + q*4]   = vsv[q];
        *(floatx4*)&out[2*BH + idx + q*4] = vcv[q];
    }
}

extern "C" void kernel_launch(void* const* d_in, const int* in_sizes, int n_in,
                              void* d_out, int out_size, void* d_ws, size_t ws_size,
                              hipStream_t stream) {
    const float* inputs = (const float*)d_in[0];
    const float* states = (const float*)d_in[1];
    const float* Wi = (const float*)d_in[2];
    const float* Ui = (const float*)d_in[3];
    const float* bi = (const float*)d_in[4];
    const float* Wf = (const float*)d_in[5];
    const float* Uf = (const float*)d_in[6];
    const float* bf = (const float*)d_in[7];
    const float* Wg = (const float*)d_in[8];
    const float* Ug = (const float*)d_in[9];
    const float* bg = (const float*)d_in[10];
    const float* Wc = (const float*)d_in[11];
    const float* Uc = (const float*)d_in[12];
    const float* bc = (const float*)d_in[13];
    float* out = (float*)d_out;

    const size_t need = (AB_ELEMS + 4 * PPLANE) * 2;   // ~37.5 MiB
    if (ws_size >= need) {
        unsigned short* Ab = (unsigned short*)d_ws;
        unsigned short* P  = Ab + AB_ELEMS;
        prep_act<<<1024, 256, 0, stream>>>(inputs, states, Ab);
        gemm_fused<<<dim3(64, 4, 4), 256, 0, stream>>>(Wi, Ui, Wf, Uf,
                                                       Wg, Ug, Wc, Uc, Ab, P);
        combine_kernel<<<BH / (8 * 256), 256, 0, stream>>>(out, P, states,
                                                           bi, bf, bg, bc, 4);
    } else {
        unsigned short* P = (unsigned short*)d_ws;
        const int nz = (ws_size >= 4 * PLANE_BYTES) ? 4 : 2;
        const int KB = 4096 / nz;
        dim3 grid(64, 4, nz);
        gemm_tile<<<grid, 256, 0, stream>>>(inputs, states, Wi, Ui, Wf, Uf,
                                            Wg, Ug, Wc, Uc, P, KB);
        combine_kernel<<<BH / (8 * 256), 256, 0, stream>>>(out, P, states,
                                                           bi, bf, bg, bc, nz);
    }
}

// Round 8
// 242.693 us; speedup vs baseline: 1.1005x; 1.1005x over previous
//
#include <hip/hip_runtime.h>

#define BH (512*2048)
#define BHA 1048576ull                   // 512*2048 elems (one activation plane)
#define PPLANE (512ull*8192ull)          // elems per partial plane [512][8192]
#define PLANE_BYTES (PPLANE*2ull)        // bf16
#define WT_ELEMS (8ull*2048*2048)        // transposed bf16 weights (8 matrices)
#define AB_ELEMS (2ull*512*2048)         // bf16 activations (inputs + prevstate)

typedef __attribute__((ext_vector_type(8))) short short8;
typedef __attribute__((ext_vector_type(4))) float floatx4;
typedef __attribute__((ext_vector_type(4))) unsigned int uint4v;
typedef __attribute__((ext_vector_type(8))) unsigned short ushort8v;

#define GLOAD_LDS16(g, l) __builtin_amdgcn_global_load_lds( \
    (const __attribute__((address_space(1))) unsigned int*)(g), \
    (__attribute__((address_space(3))) unsigned int*)(l), 16, 0, 0)

// pack two f32 -> two bf16 (round-half-up) in one dword (verified R2-R4)
__device__ inline unsigned pk2(float a, float b){
    unsigned ua = __builtin_bit_cast(unsigned, a) + 0x8000u;
    unsigned ub = __builtin_bit_cast(unsigned, b) + 0x8000u;
    return __builtin_amdgcn_perm(ub, ua, 0x07060302u);
}
__device__ inline unsigned short f2bf1(float x){
    return (unsigned short)((__builtin_bit_cast(unsigned, x) + 0x8000u) >> 16);
}
__device__ inline float bf2f(unsigned short s){
    return __builtin_bit_cast(float, ((unsigned)s) << 16);
}
__device__ inline int swz(int r, int g){ return r*4 + (g ^ ((r>>1)&3)); }
__device__ inline float fsig(float x){ return __builtin_amdgcn_rcpf(1.f + __expf(-x)); }
__device__ inline float ftanh(float x){ return 2.f*fsig(2.f*x) - 1.f; }

// ---------------------------------------------------------------------------
// Prepass R7 (channel-dense streamer) — resubmitted after infra failure.
// bid < 2048: one [32k x 512n] fp32 weight panel -> transposed bf16 tiles.
//   mat = bid>>8 ({Wi,Wf,Wg,Wc,Ui,Uf,Ug,Uc}), rowblk = (bid>>2)&63, nq=bid&3.
//   nq is the FASTEST grid dim so co-dispatched blocks cover complete 8KB
//   rows -> aggregate HBM read order is linear (channel-dense).
//   Phase 1: 16 x 1KB-per-wave float4 row reads -> pk2 -> LDS [k][257-pad]
//   dwords (dword p holds cols 2p,2p+1 of row k; banks (k+2c)%32, free).
//   Phase 2: thread t owns col-pair p=t: 32 ds_read_b32 (banks (j+t)%32,
//   free) + 32 v_perm -> rows n0=2t, n0+1 -> one 128B dense global write.
//   Output layout identical to R0 Wt: tile ((gate*16+nb)*128+kt) =
//   [n_loc 0..127][k_loc 0..31] 8KB; kt<64 = W rows kt*32, kt>=64 = U.
// bid >= 2048: cast inputs (plane 0) / states[0] (plane 1) to bf16 flat.
// ---------------------------------------------------------------------------
__global__ __launch_bounds__(256) void prep(
    const float* __restrict__ inputs, const float* __restrict__ states,
    const float* __restrict__ Wi, const float* __restrict__ Ui,
    const float* __restrict__ Wf, const float* __restrict__ Uf,
    const float* __restrict__ Wg, const float* __restrict__ Ug,
    const float* __restrict__ Wc, const float* __restrict__ Uc,
    unsigned short* __restrict__ Wt, unsigned short* __restrict__ Ab)
{
    __shared__ unsigned lds32[32 * 257];   // 32,896 B -> 4 blocks/CU
    const int bid = blockIdx.x, t = threadIdx.x;
    if (bid < 2048) {
        const int mat = bid >> 8, rowblk = (bid >> 2) & 63, nq = bid & 3;
        const float* src;
        switch (mat) {
            case 0: src = Wi; break; case 1: src = Wf; break;
            case 2: src = Wg; break; case 3: src = Wc; break;
            case 4: src = Ui; break; case 5: src = Uf; break;
            case 6: src = Ug; break; default: src = Uc; break;
        }
        const int gate = mat & 3, kt = rowblk + (mat >> 2) * 64;
        const float* sb = src + (size_t)(rowblk * 32) * 2048 + nq * 512;

        // phase 1: 16 fully-coalesced float4 loads (1KB/wave/instr)
        floatx4 v[16];
        #pragma unroll
        for (int i = 0; i < 16; i++) {
            const int idx = t + 256 * i;
            const int k = idx >> 7, c4 = idx & 127;
            v[i] = *(const floatx4*)(sb + (size_t)k * 2048 + c4 * 4);
        }
        #pragma unroll
        for (int i = 0; i < 16; i++) {
            const int idx = t + 256 * i;
            const int k = idx >> 7, c4 = idx & 127;
            lds32[k * 257 + c4 * 2]     = pk2(v[i][0], v[i][1]);
            lds32[k * 257 + c4 * 2 + 1] = pk2(v[i][2], v[i][3]);
        }
        __syncthreads();

        // phase 2: column-pair gather (conflict-free) + perm split
        unsigned d[32];
        #pragma unroll
        for (int j = 0; j < 32; j++) d[j] = lds32[j * 257 + t];
        unsigned lo[16], hi[16];
        #pragma unroll
        for (int m = 0; m < 16; m++) {
            lo[m] = __builtin_amdgcn_perm(d[2*m+1], d[2*m], 0x05040100u);
            hi[m] = __builtin_amdgcn_perm(d[2*m+1], d[2*m], 0x07060302u);
        }
        const int n0 = nq * 512 + 2 * t;
        const int tile = (gate * 16 + (n0 >> 7)) * 128 + kt;
        unsigned short* op = Wt + (size_t)tile * 4096 + (size_t)(n0 & 127) * 32;
        *(uint4v*)(op)      = (uint4v){lo[0], lo[1], lo[2],  lo[3]};
        *(uint4v*)(op + 8)  = (uint4v){lo[4], lo[5], lo[6],  lo[7]};
        *(uint4v*)(op + 16) = (uint4v){lo[8], lo[9], lo[10], lo[11]};
        *(uint4v*)(op + 24) = (uint4v){lo[12],lo[13],lo[14], lo[15]};
        *(uint4v*)(op + 32) = (uint4v){hi[0], hi[1], hi[2],  hi[3]};
        *(uint4v*)(op + 40) = (uint4v){hi[4], hi[5], hi[6],  hi[7]};
        *(uint4v*)(op + 48) = (uint4v){hi[8], hi[9], hi[10], hi[11]};
        *(uint4v*)(op + 56) = (uint4v){hi[12],hi[13],hi[14], hi[15]};
    } else {
        const size_t off = ((size_t)(bid - 2048) * 256 + t) * 8;
        const float* src = (off < BHA) ? (inputs + off) : (states + (off - BHA));
        floatx4 v0 = *(const floatx4*)src;
        floatx4 v1 = *(const floatx4*)(src + 4);
        uint4v w;
        w.x = pk2(v0[0],v0[1]); w.y = pk2(v0[2],v0[3]);
        w.z = pk2(v1[0],v1[1]); w.w = pk2(v1[2],v1[3]);
        *(uint4v*)(Ab + off) = w;
    }
}

// ---------------------------------------------------------------------------
// Main GEMM (bf16 pre-converted inputs): R0's proven kernel, unchanged.
// Block 128x128, 4 waves of 64x64 (4x4 x mfma_16x16x32_bf16), BK=32,
// double-buffered LDS filled by global_load_lds width-16, one barrier/iter.
// ---------------------------------------------------------------------------
__global__ __launch_bounds__(256, 4) void gemm_lds(
    const unsigned short* __restrict__ Wt, const unsigned short* __restrict__ Ab,
    unsigned short* __restrict__ P)
{
    __shared__ unsigned short As[2][4096];   // [m 0..127][k 0..31]
    __shared__ unsigned short Bs[2][4096];   // [n 0..127][k 0..31]

    const int t = threadIdx.x, lane = t & 63, wave = t >> 6;
    const int nblk = blockIdx.x, gate = nblk >> 4, nb = nblk & 15;
    const int m0 = blockIdx.y * 128, z = blockIdx.z;

    const unsigned short* Bt = Wt + ((size_t)(gate*16 + nb) * 128 + z*32) * 4096;
    const unsigned short* Abase = Ab + (size_t)(z >> 1) * BHA
                                     + (size_t)m0 * 2048 + (z & 1) * 1024;

    const int i0 = wave * 2, i1 = wave * 2 + 1;   // this wave's two DMA slots
    const unsigned short* ag0 = Abase + (size_t)(i0*16 + (lane>>2)) * 2048 + (lane&3)*8;
    const unsigned short* ag1 = Abase + (size_t)(i1*16 + (lane>>2)) * 2048 + (lane&3)*8;
    const unsigned short* bg0 = Bt + i0*512 + lane*8;
    const unsigned short* bg1 = Bt + i1*512 + lane*8;

    floatx4 acc[4][4];
    #pragma unroll
    for (int i = 0; i < 4; i++)
        #pragma unroll
        for (int j = 0; j < 4; j++)
            acc[i][j] = (floatx4){0.f,0.f,0.f,0.f};

    const int wm = (wave & 1) * 64, wn = (wave >> 1) * 64;
    const int row16 = lane & 15, g4 = lane >> 4;

    // prologue: DMA tile 0 into buf 0
    GLOAD_LDS16(ag0, &As[0][i0*512]);
    GLOAD_LDS16(ag1, &As[0][i1*512]);
    GLOAD_LDS16(bg0, &Bs[0][i0*512]);
    GLOAD_LDS16(bg1, &Bs[0][i1*512]);
    __syncthreads();

    for (int kk = 0; kk < 32; kk++) {
        const int cur = kk & 1;
        if (kk < 31) {                       // DMA next tile into other buffer
            const int nxt = cur ^ 1;
            GLOAD_LDS16(ag0 + (kk+1)*32,   &As[nxt][i0*512]);
            GLOAD_LDS16(ag1 + (kk+1)*32,   &As[nxt][i1*512]);
            GLOAD_LDS16(bg0 + (kk+1)*4096, &Bs[nxt][i0*512]);
            GLOAD_LDS16(bg1 + (kk+1)*4096, &Bs[nxt][i1*512]);
        }
        short8 afr[4], bfr[4];
        #pragma unroll
        for (int mi = 0; mi < 4; mi++)
            afr[mi] = *(const short8*)&As[cur][(wm + mi*16 + row16)*32 + g4*8];
        #pragma unroll
        for (int ni = 0; ni < 4; ni++)
            bfr[ni] = *(const short8*)&Bs[cur][(wn + ni*16 + row16)*32 + g4*8];
        #pragma unroll
        for (int mi = 0; mi < 4; mi++)
            #pragma unroll
            for (int ni = 0; ni < 4; ni++)
                acc[mi][ni] = __builtin_amdgcn_mfma_f32_16x16x32_bf16(
                    afr[mi], bfr[ni], acc[mi][ni], 0, 0, 0);
        __syncthreads();                     // drains DMA (vmcnt) + barrier
    }

    unsigned short* dst = P + (size_t)z * PPLANE;
    const int gbase = gate * 2048 + nb * 128;
    #pragma unroll
    for (int mi = 0; mi < 4; mi++)
        #pragma unroll
        for (int ni = 0; ni < 4; ni++)
            #pragma unroll
            for (int j = 0; j < 4; j++) {
                int row = m0 + wm + mi*16 + g4*4 + j;
                int col = gbase + wn + ni*16 + row16;
                dst[(size_t)row * 8192 + col] = f2bf1(acc[mi][ni][j]);
            }
}

// ---------------------------------------------------------------------------
// Fallback GEMM (fused fp32 staging) for small ws_size.
// ---------------------------------------------------------------------------
__global__ __launch_bounds__(256, 2) void gemm_tile(
    const float* __restrict__ inputs, const float* __restrict__ states,
    const float* __restrict__ Wi, const float* __restrict__ Ui,
    const float* __restrict__ Wf, const float* __restrict__ Uf,
    const float* __restrict__ Wg, const float* __restrict__ Ug,
    const float* __restrict__ Wc, const float* __restrict__ Uc,
    unsigned short* __restrict__ P, int KB)
{
    __shared__ uint4v As[2][512];
    __shared__ uint4v Bs[2][512];

    const int t = threadIdx.x;
    const int m0 = blockIdx.y * 128;
    const int z = blockIdx.z;
    const int nblk = blockIdx.x;
    const int gate = nblk >> 4;
    const int c0 = (nblk & 15) * 128;
    const int gk = z * KB;

    const float* Abase; const float* Bsel; int ko;
    if (gk < 2048) {
        Abase = inputs; ko = gk;
        switch (gate){ case 0: Bsel=Wi; break; case 1: Bsel=Wf; break;
                       case 2: Bsel=Wg; break; default: Bsel=Wc; }
    } else {
        Abase = states; ko = gk - 2048;
        switch (gate){ case 0: Bsel=Ui; break; case 1: Bsel=Uf; break;
                       case 2: Bsel=Ug; break; default: Bsel=Uc; }
    }
    const int NIT = KB >> 5;

    const int lane = t & 63, wave = t >> 6;
    const int wm = (wave & 1) * 64, wn = (wave >> 1) * 64;
    const int row16 = lane & 15, g4 = lane >> 4;
    const int ar = t >> 2, ag = t & 3;
    const int bn = t & 127, bg2 = (t >> 7) * 2;

    const float* Ap = Abase + (size_t)(m0 + ar) * 2048 + ko + ag * 8;
    const float* Bp = Bsel + (size_t)ko * 2048 + c0 + bn;

    floatx4 acc[4][4];
    #pragma unroll
    for (int i = 0; i < 4; i++)
        #pragma unroll
        for (int j = 0; j < 4; j++)
            acc[i][j] = (floatx4){0.f,0.f,0.f,0.f};

    floatx4 a0,a1,a2,a3; float b0[8], b1[8];
    a0 = *(const floatx4*)Ap;             a1 = *(const floatx4*)(Ap + 4);
    a2 = *(const floatx4*)(Ap + 64*2048); a3 = *(const floatx4*)(Ap + 64*2048 + 4);
    #pragma unroll
    for (int j = 0; j < 8; j++) b0[j] = Bp[(size_t)(bg2*8 + j) * 2048];
    #pragma unroll
    for (int j = 0; j < 8; j++) b1[j] = Bp[(size_t)(bg2*8 + 8 + j) * 2048];
    {
        uint4v w;
        w.x=pk2(a0[0],a0[1]); w.y=pk2(a0[2],a0[3]); w.z=pk2(a1[0],a1[1]); w.w=pk2(a1[2],a1[3]);
        As[0][swz(ar, ag)] = w;
        w.x=pk2(a2[0],a2[1]); w.y=pk2(a2[2],a2[3]); w.z=pk2(a3[0],a3[1]); w.w=pk2(a3[2],a3[3]);
        As[0][swz(ar+64, ag)] = w;
        w.x=pk2(b0[0],b0[1]); w.y=pk2(b0[2],b0[3]); w.z=pk2(b0[4],b0[5]); w.w=pk2(b0[6],b0[7]);
        Bs[0][swz(bn, bg2)] = w;
        w.x=pk2(b1[0],b1[1]); w.y=pk2(b1[2],b1[3]); w.z=pk2(b1[4],b1[5]); w.w=pk2(b1[6],b1[7]);
        Bs[0][swz(bn, bg2+1)] = w;
    }

    for (int kk = 0; kk < NIT; kk++) {
        __syncthreads();
        const int cur = kk & 1;
        if (kk + 1 < NIT) {
            const float* ap = Ap + (kk+1) * 32;
            a0 = *(const floatx4*)ap;             a1 = *(const floatx4*)(ap + 4);
            a2 = *(const floatx4*)(ap + 64*2048); a3 = *(const floatx4*)(ap + 64*2048 + 4);
            const float* bp = Bp + (size_t)(kk+1) * 32 * 2048;
            #pragma unroll
            for (int j = 0; j < 8; j++) b0[j] = bp[(size_t)(bg2*8 + j) * 2048];
            #pragma unroll
            for (int j = 0; j < 8; j++) b1[j] = bp[(size_t)(bg2*8 + 8 + j) * 2048];
        }
        short8 afr[4], bfr[4];
        #pragma unroll
        for (int mi = 0; mi < 4; mi++)
            afr[mi] = *(const short8*)&As[cur][swz(wm + mi*16 + row16, g4)];
        #pragma unroll
        for (int ni = 0; ni < 4; ni++)
            bfr[ni] = *(const short8*)&Bs[cur][swz(wn + ni*16 + row16, g4)];
        #pragma unroll
        for (int mi = 0; mi < 4; mi++)
            #pragma unroll
            for (int ni = 0; ni < 4; ni++)
                acc[mi][ni] = __builtin_amdgcn_mfma_f32_16x16x32_bf16(
                    afr[mi], bfr[ni], acc[mi][ni], 0, 0, 0);
        if (kk + 1 < NIT) {
            const int nxt = cur ^ 1;
            uint4v w;
            w.x=pk2(a0[0],a0[1]); w.y=pk2(a0[2],a0[3]); w.z=pk2(a1[0],a1[1]); w.w=pk2(a1[2],a1[3]);
            As[nxt][swz(ar, ag)] = w;
            w.x=pk2(a2[0],a2[1]); w.y=pk2(a2[2],a2[3]); w.z=pk2(a3[0],a3[1]); w.w=pk2(a3[2],a3[3]);
            As[nxt][swz(ar+64, ag)] = w;
            w.x=pk2(b0[0],b0[1]); w.y=pk2(b0[2],b0[3]); w.z=pk2(b0[4],b0[5]); w.w=pk2(b0[6],b0[7]);
            Bs[nxt][swz(bn, bg2)] = w;
            w.x=pk2(b1[0],b1[1]); w.y=pk2(b1[2],b1[3]); w.z=pk2(b1[4],b1[5]); w.w=pk2(b1[6],b1[7]);
            Bs[nxt][swz(bn, bg2+1)] = w;
        }
    }

    unsigned short* dst = P + (size_t)z * PPLANE;
    const int gbase = gate * 2048 + c0;
    #pragma unroll
    for (int mi = 0; mi < 4; mi++)
        #pragma unroll
        for (int ni = 0; ni < 4; ni++)
            #pragma unroll
            for (int j = 0; j < 4; j++) {
                int row = m0 + wm + mi*16 + g4*4 + j;
                int col = gbase + wn + ni*16 + row16;
                dst[(size_t)row * 8192 + col] = f2bf1(acc[mi][ni][j]);
            }
}

// activations + LSTM combine
__global__ __launch_bounds__(256) void combine_kernel(
    float* __restrict__ out, const unsigned short* __restrict__ P,
    const float* __restrict__ states,
    const float* __restrict__ bi, const float* __restrict__ bfv,
    const float* __restrict__ bg, const float* __restrict__ bc, int nz)
{
    const int idx = (blockIdx.x * 256 + threadIdx.x) * 8;
    const int row = idx >> 11;
    const int h = idx & 2047;
    const size_t base = (size_t)row * 8192 + h;

    float xi[8], xf[8], xg[8], xc[8];
    #pragma unroll
    for (int e = 0; e < 8; e++) {
        xi[e] = bi[h+e]; xf[e] = bfv[h+e]; xg[e] = bg[h+e]; xc[e] = bc[h+e];
    }
    for (int z = 0; z < nz; z++) {
        const unsigned short* Pz = P + (size_t)z * PPLANE;
        ushort8v vi = *(const ushort8v*)&Pz[base];
        ushort8v vf = *(const ushort8v*)&Pz[base + 2048];
        ushort8v vg = *(const ushort8v*)&Pz[base + 4096];
        ushort8v vc = *(const ushort8v*)&Pz[base + 6144];
        #pragma unroll
        for (int e = 0; e < 8; e++) {
            xi[e] += bf2f(vi[e]); xf[e] += bf2f(vf[e]);
            xg[e] += bf2f(vg[e]); xc[e] += bf2f(vc[e]);
        }
    }

    const float* po = states + BH;
    floatx4 pov[2];
    pov[0] = *(const floatx4*)&po[idx];
    pov[1] = *(const floatx4*)&po[idx + 4];

    floatx4 vcv[2], vsv[2];
    #pragma unroll
    for (int q = 0; q < 2; q++)
        #pragma unroll
        for (int j = 0; j < 4; j++) {
            int e = q*4 + j;
            float c = fsig(xf[e]) * pov[q][j] + fsig(xi[e]) * ftanh(xc[e]);
            vcv[q][j] = c;
            vsv[q][j] = fsig(xg[e]) * ftanh(c);
        }
    #pragma unroll
    for (int q = 0; q < 2; q++) {
        *(floatx4*)&out[idx + q*4]        = vcv[q];
        *(floatx4*)&out[BH + idx + q*4]   = vsv[q];
        *(floatx4*)&out[2*BH + idx + q*4] = vcv[q];
    }
}

extern "C" void kernel_launch(void* const* d_in, const int* in_sizes, int n_in,
                              void* d_out, int out_size, void* d_ws, size_t ws_size,
                              hipStream_t stream) {
    const float* inputs = (const float*)d_in[0];
    const float* states = (const float*)d_in[1];
    const float* Wi = (const float*)d_in[2];
    const float* Ui = (const float*)d_in[3];
    const float* bi = (const float*)d_in[4];
    const float* Wf = (const float*)d_in[5];
    const float* Uf = (const float*)d_in[6];
    const float* bf = (const float*)d_in[7];
    const float* Wg = (const float*)d_in[8];
    const float* Ug = (const float*)d_in[9];
    const float* bg = (const float*)d_in[10];
    const float* Wc = (const float*)d_in[11];
    const float* Uc = (const float*)d_in[12];
    const float* bc = (const float*)d_in[13];
    float* out = (float*)d_out;

    const size_t need = (WT_ELEMS + AB_ELEMS + 4 * PPLANE) * 2;   // 100 MiB
    if (ws_size >= need) {
        unsigned short* Wt = (unsigned short*)d_ws;
        unsigned short* Ab = Wt + WT_ELEMS;
        unsigned short* P  = Ab + AB_ELEMS;
        prep<<<3072, 256, 0, stream>>>(inputs, states, Wi, Ui, Wf, Uf,
                                       Wg, Ug, Wc, Uc, Wt, Ab);
        gemm_lds<<<dim3(64, 4, 4), 256, 0, stream>>>(Wt, Ab, P);
        combine_kernel<<<BH / (8 * 256), 256, 0, stream>>>(out, P, states,
                                                           bi, bf, bg, bc, 4);
    } else {
        unsigned short* P = (unsigned short*)d_ws;
        const int nz = (ws_size >= 4 * PLANE_BYTES) ? 4 : 2;
        const int KB = 4096 / nz;
        dim3 grid(64, 4, nz);
        gemm_tile<<<grid, 256, 0, stream>>>(inputs, states, Wi, Ui, Wf, Uf,
                                            Wg, Ug, Wc, Uc, P, KB);
        combine_kernel<<<BH / (8 * 256), 256, 0, stream>>>(out, P, states,
                                                           bi, bf, bg, bc, nz);
    }
}